// Round 1
// baseline (535.283 us; speedup 1.0000x reference)
//
#include <hip/hip_runtime.h>
#include <hip/hip_bf16.h>
#include <stdint.h>

// ---------------------------------------------------------------------------
// LoRALinear: y = x @ (W + B@A)^T + (b + lora_bias)
// M = 4*2048 = 8192, K = 4096, N = 4096, rank 16, scaling 1.0
//
// Plan:
//   1) conv_w:   Wb' = bf16(W + B@A)      [4096,4096] bf16 into ws
//   2) conv_x:   Xb  = bf16(x)            [8192,4096] bf16 into ws
//   3) conv_b:   bias' = b + lora_bias    [4096] f32 into ws
//   4) gemm:     m97-structure 128x128 tile bf16 MFMA GEMM, fp32 out + bias
// Fallback (ws too small): naive fp32 kernel (slow but correct).
// ---------------------------------------------------------------------------

#define M_DIM 8192
#define N_DIM 4096
#define K_DIM 4096

typedef __attribute__((ext_vector_type(8))) short bf16x8;
typedef __attribute__((ext_vector_type(4))) float f32x4;

static __device__ __forceinline__ unsigned short f2bf(float f) {
    unsigned int u = __builtin_bit_cast(unsigned int, f);
    unsigned int r = (u + 0x7fffu + ((u >> 16) & 1u)) >> 16;
    return (unsigned short)r;
}

// --- 1) W' = bf16(W + B@A) --------------------------------------------------
// grid: 4096 blocks (one output row n), 256 threads, each thread does 16 k's.
__global__ __launch_bounds__(256) void conv_w_kernel(
    const float* __restrict__ W, const float* __restrict__ lA,
    const float* __restrict__ lB, unsigned short* __restrict__ Wb) {
    const int n = blockIdx.x;
    const int k0 = threadIdx.x * 16;

    float br[16];
#pragma unroll
    for (int r = 0; r < 16; ++r) br[r] = lB[(size_t)n * 16 + r];

    float acc[16];
    const float4* w4 = (const float4*)(W + (size_t)n * K_DIM + k0);
#pragma unroll
    for (int j = 0; j < 4; ++j) {
        float4 v = w4[j];
        acc[j * 4 + 0] = v.x; acc[j * 4 + 1] = v.y;
        acc[j * 4 + 2] = v.z; acc[j * 4 + 3] = v.w;
    }
#pragma unroll
    for (int r = 0; r < 16; ++r) {
        const float4* a4 = (const float4*)(lA + (size_t)r * K_DIM + k0);
#pragma unroll
        for (int j = 0; j < 4; ++j) {
            float4 v = a4[j];
            acc[j * 4 + 0] += br[r] * v.x; acc[j * 4 + 1] += br[r] * v.y;
            acc[j * 4 + 2] += br[r] * v.z; acc[j * 4 + 3] += br[r] * v.w;
        }
    }
    union { unsigned short us[16]; uint4 v[2]; } u;
#pragma unroll
    for (int j = 0; j < 16; ++j) u.us[j] = f2bf(acc[j]);
    uint4* dst = (uint4*)(Wb + (size_t)n * K_DIM + k0);
    dst[0] = u.v[0];
    dst[1] = u.v[1];
}

// --- 2) Xb = bf16(x) --------------------------------------------------------
__global__ __launch_bounds__(256) void conv_x_kernel(
    const float* __restrict__ x, unsigned short* __restrict__ xb) {
    size_t i = ((size_t)blockIdx.x * 256 + threadIdx.x) * 8;
    float4 a = *(const float4*)(x + i);
    float4 c = *(const float4*)(x + i + 4);
    union { unsigned short us[8]; uint4 v; } u;
    u.us[0] = f2bf(a.x); u.us[1] = f2bf(a.y); u.us[2] = f2bf(a.z); u.us[3] = f2bf(a.w);
    u.us[4] = f2bf(c.x); u.us[5] = f2bf(c.y); u.us[6] = f2bf(c.z); u.us[7] = f2bf(c.w);
    *(uint4*)(xb + i) = u.v;
}

// --- 3) bias' = b + lora_bias ----------------------------------------------
__global__ __launch_bounds__(256) void conv_b_kernel(
    const float* __restrict__ b, const float* __restrict__ lb,
    float* __restrict__ biasw) {
    int i = blockIdx.x * 256 + threadIdx.x;
    if (i < N_DIM) biasw[i] = b[i] + lb[i];
}

// --- 4) GEMM: C[m][n] = sum_k Xb[m][k]*Wb[n][k] + bias[n] -------------------
// m97 structure: 128x128 tile, BK=64, 4 waves (2x2), 16x16x32 bf16 MFMA,
// global_load_lds width=16 staging, linear LDS, 2 barriers per K-step.
__global__ __launch_bounds__(256) void gemm_kernel(
    const unsigned short* __restrict__ A,   // [8192][4096] bf16
    const unsigned short* __restrict__ B,   // [4096][4096] bf16 (W', N-major)
    const float* __restrict__ bias,         // [4096]
    float* __restrict__ C) {                // [8192][4096] f32
    const int ntile = blockIdx.x;           // 0..31
    const int mtile = blockIdx.y;           // 0..63
    const int m0 = mtile * 128, n0 = ntile * 128;
    const int tid = threadIdx.x;
    const int lane = tid & 63;
    const int wid = tid >> 6;               // 0..3
    const int wr = wid >> 1, wc = wid & 1;  // wave -> 64x64 quadrant

    __shared__ __align__(16) unsigned short ldsA[128 * 64];
    __shared__ __align__(16) unsigned short ldsB[128 * 64];

    f32x4 acc[4][4] = {};

    const int lrow_q = lane & 15;   // fragment row/col within 16
    const int lk8 = (lane >> 4) * 8;  // k sub-offset within 32

    for (int k0 = 0; k0 < K_DIM; k0 += 64) {
        // ---- stage A,B tiles: 16 chunks of 1024B each per tile ----
#pragma unroll
        for (int r = 0; r < 4; ++r) {
            const int c = r * 4 + wid;           // wave-uniform chunk id
            const int idx = c * 64 + lane;
            const int row = idx >> 3;            // tile row 0..127
            const int kcol = (idx & 7) * 8;      // k element offset 0..56
            const unsigned short* gA = A + (size_t)(m0 + row) * K_DIM + k0 + kcol;
            const unsigned short* gB = B + (size_t)(n0 + row) * K_DIM + k0 + kcol;
            __builtin_amdgcn_global_load_lds(
                (const __attribute__((address_space(1))) void*)gA,
                (__attribute__((address_space(3))) void*)(ldsA + c * 512), 16, 0, 0);
            __builtin_amdgcn_global_load_lds(
                (const __attribute__((address_space(1))) void*)gB,
                (__attribute__((address_space(3))) void*)(ldsB + c * 512), 16, 0, 0);
        }
        __syncthreads();

        // ---- compute: 2 K-substeps of 32 ----
#pragma unroll
        for (int kk = 0; kk < 2; ++kk) {
            bf16x8 af[4], bf[4];
#pragma unroll
            for (int m = 0; m < 4; ++m) {
                int row = wr * 64 + m * 16 + lrow_q;
                af[m] = *(const bf16x8*)(ldsA + row * 64 + kk * 32 + lk8);
            }
#pragma unroll
            for (int n = 0; n < 4; ++n) {
                int row = wc * 64 + n * 16 + lrow_q;
                bf[n] = *(const bf16x8*)(ldsB + row * 64 + kk * 32 + lk8);
            }
#pragma unroll
            for (int m = 0; m < 4; ++m)
#pragma unroll
                for (int n = 0; n < 4; ++n)
                    acc[m][n] = __builtin_amdgcn_mfma_f32_16x16x32_bf16(
                        af[m], bf[n], acc[m][n], 0, 0, 0);
        }
        __syncthreads();
    }

    // ---- epilogue: C/D layout col=lane&15, row=(lane>>4)*4+reg ----
#pragma unroll
    for (int n = 0; n < 4; ++n) {
        int gc = n0 + wc * 64 + n * 16 + (lane & 15);
        float bv = bias[gc];
#pragma unroll
        for (int m = 0; m < 4; ++m) {
            int gr0 = m0 + wr * 64 + m * 16 + (lane >> 4) * 4;
            f32x4 v = acc[m][n];
#pragma unroll
            for (int j = 0; j < 4; ++j)
                C[(size_t)(gr0 + j) * N_DIM + gc] = v[j] + bv;
        }
    }
}

// --- Fallback: naive fp32, correct but slow (only if ws too small) ----------
__global__ __launch_bounds__(256) void naive_kernel(
    const float* __restrict__ x, const float* __restrict__ W,
    const float* __restrict__ b, const float* __restrict__ lA,
    const float* __restrict__ lB, const float* __restrict__ lb,
    float* __restrict__ out) {
    __shared__ float xs[K_DIM];
    __shared__ float ts[16];
    const int m = blockIdx.x;
    const int tid = threadIdx.x;
    for (int k = tid; k < K_DIM; k += 256) xs[k] = x[(size_t)m * K_DIM + k];
    if (tid < 16) ts[tid] = 0.f;
    __syncthreads();
    float part[16] = {};
    for (int k = tid * 16; k < tid * 16 + 16; ++k) {
        float xv = xs[k];
#pragma unroll
        for (int r = 0; r < 16; ++r) part[r] += xv * lA[(size_t)r * K_DIM + k];
    }
#pragma unroll
    for (int r = 0; r < 16; ++r) atomicAdd(&ts[r], part[r]);
    __syncthreads();
    const int n = blockIdx.y * 256 + tid;
    float acc = b[n] + lb[n];
#pragma unroll
    for (int r = 0; r < 16; ++r) acc += ts[r] * lB[(size_t)n * 16 + r];
    const float* wrow = W + (size_t)n * K_DIM;
    for (int k = 0; k < K_DIM; ++k) acc += xs[k] * wrow[k];
    out[(size_t)m * N_DIM + n] = acc;
}

// ---------------------------------------------------------------------------
extern "C" void kernel_launch(void* const* d_in, const int* in_sizes, int n_in,
                              void* d_out, int out_size, void* d_ws, size_t ws_size,
                              hipStream_t stream) {
    const float* x  = (const float*)d_in[0];
    const float* W  = (const float*)d_in[1];
    const float* b  = (const float*)d_in[2];
    const float* lA = (const float*)d_in[3];
    const float* lB = (const float*)d_in[4];
    const float* lb = (const float*)d_in[5];
    float* out = (float*)d_out;

    const size_t xb_bytes = (size_t)M_DIM * K_DIM * 2;  // 64 MiB
    const size_t wb_bytes = (size_t)N_DIM * K_DIM * 2;  // 32 MiB
    const size_t bias_bytes = (size_t)N_DIM * 4;

    if (ws_size >= xb_bytes + wb_bytes + bias_bytes) {
        unsigned short* xb = (unsigned short*)d_ws;
        unsigned short* wb = (unsigned short*)((char*)d_ws + xb_bytes);
        float* biasw = (float*)((char*)d_ws + xb_bytes + wb_bytes);

        conv_x_kernel<<<(M_DIM * K_DIM) / (256 * 8), 256, 0, stream>>>(x, xb);
        conv_w_kernel<<<N_DIM, 256, 0, stream>>>(W, lA, lB, wb);
        conv_b_kernel<<<(N_DIM + 255) / 256, 256, 0, stream>>>(b, lb, biasw);

        dim3 grid(N_DIM / 128, M_DIM / 128);  // (32, 64)
        gemm_kernel<<<grid, 256, 0, stream>>>(xb, wb, biasw, out);
    } else {
        dim3 grid(M_DIM, N_DIM / 256);
        naive_kernel<<<grid, 256, 0, stream>>>(x, W, b, lA, lB, lb, out);
    }
}

// Round 3
// 331.771 us; speedup vs baseline: 1.6134x; 1.6134x over previous
//
#include <hip/hip_runtime.h>
#include <hip/hip_bf16.h>
#include <stdint.h>

// ---------------------------------------------------------------------------
// LoRALinear: y = x @ (W + B@A)^T + (b + lora_bias)
// M=8192, N=4096, K=4096.
// conv_x: x -> bf16; conv_w: bf16(W + B@A); gemm: 256x256 8-phase MFMA
// (T1 XCD swizzle + T2 st-swizzle + T3/T4 counted vmcnt + T5 setprio),
// bias fused in epilogue.
// R2 fix: B read-side 64-row sub-block offset is (wc&1)*4096 elements
// (was 8192 -> odd-wc waves read wrong half-tile / past end of ldsB).
// ---------------------------------------------------------------------------

#define M_DIM 8192
#define N_DIM 4096
#define K_DIM 4096
#define NT    (K_DIM / 64)   // 64 K-tiles

typedef __attribute__((ext_vector_type(8))) short bf16x8;
typedef __attribute__((ext_vector_type(4))) float f32x4;

#define PH_BAR() asm volatile("s_barrier" ::: "memory")
#define WAITV8() asm volatile("s_waitcnt vmcnt(8)" ::: "memory")
#define WAITV0() asm volatile("s_waitcnt vmcnt(0)" ::: "memory")

static __device__ __forceinline__ unsigned short f2bf(float f) {
    unsigned int u = __builtin_bit_cast(unsigned int, f);
    unsigned int r = (u + 0x7fffu + ((u >> 16) & 1u)) >> 16;
    return (unsigned short)r;
}

// --- conv_x: bf16(x) --------------------------------------------------------
__global__ __launch_bounds__(256) void conv_x_kernel(
    const float* __restrict__ x, unsigned short* __restrict__ xb) {
    size_t i = ((size_t)blockIdx.x * 256 + threadIdx.x) * 8;
    float4 a = *(const float4*)(x + i);
    float4 c = *(const float4*)(x + i + 4);
    union { unsigned short us[8]; uint4 v; } u;
    u.us[0] = f2bf(a.x); u.us[1] = f2bf(a.y); u.us[2] = f2bf(a.z); u.us[3] = f2bf(a.w);
    u.us[4] = f2bf(c.x); u.us[5] = f2bf(c.y); u.us[6] = f2bf(c.z); u.us[7] = f2bf(c.w);
    *(uint4*)(xb + i) = u.v;
}

// --- conv_w: bf16(W + B@A). 4 rows/block, lA read once per block. ----------
__global__ __launch_bounds__(512) void conv_w_kernel(
    const float* __restrict__ W, const float* __restrict__ lA,
    const float* __restrict__ lB, unsigned short* __restrict__ Wb) {
    const int nb = blockIdx.x * 4;        // 1024 blocks
    const int k0 = threadIdx.x * 8;       // 512 thr * 8 = 4096

    float acc[4][8];
#pragma unroll
    for (int r = 0; r < 4; ++r) {
        const float4* w4 = (const float4*)(W + (size_t)(nb + r) * K_DIM + k0);
        float4 v0 = w4[0], v1 = w4[1];
        acc[r][0] = v0.x; acc[r][1] = v0.y; acc[r][2] = v0.z; acc[r][3] = v0.w;
        acc[r][4] = v1.x; acc[r][5] = v1.y; acc[r][6] = v1.z; acc[r][7] = v1.w;
    }
    float brs[4][16];
#pragma unroll
    for (int r = 0; r < 4; ++r)
#pragma unroll
        for (int t = 0; t < 16; ++t) brs[r][t] = lB[(size_t)(nb + r) * 16 + t];

#pragma unroll
    for (int t = 0; t < 16; ++t) {
        const float4* a4 = (const float4*)(lA + (size_t)t * K_DIM + k0);
        float4 v0 = a4[0], v1 = a4[1];
        float av[8] = {v0.x, v0.y, v0.z, v0.w, v1.x, v1.y, v1.z, v1.w};
#pragma unroll
        for (int r = 0; r < 4; ++r)
#pragma unroll
            for (int j = 0; j < 8; ++j) acc[r][j] += brs[r][t] * av[j];
    }
#pragma unroll
    for (int r = 0; r < 4; ++r) {
        union { unsigned short us[8]; uint4 v; } u;
#pragma unroll
        for (int j = 0; j < 8; ++j) u.us[j] = f2bf(acc[r][j]);
        *(uint4*)(Wb + (size_t)(nb + r) * K_DIM + k0) = u.v;
    }
}

// --- gemm: 256x256 tile, BK=64, 8 waves, 8-phase counted-vmcnt schedule -----
__global__ __launch_bounds__(512, 2) void gemm_kernel(
    const unsigned short* __restrict__ A,   // [8192][4096] bf16
    const unsigned short* __restrict__ B,   // [4096][4096] bf16 (W')
    const float* __restrict__ bvec, const float* __restrict__ lbvec,
    float* __restrict__ C) {
    const int tid = threadIdx.x;
    const int lane = tid & 63;
    const int wid = tid >> 6;        // 0..7
    const int wr = wid >> 2;         // 0..1  M-half
    const int wc = wid & 3;          // 0..3  N-quarter

    // T1: bijective XCD swizzle (512 % 8 == 0)
    const int bid = blockIdx.x;
    const int wg = (bid & 7) * 64 + (bid >> 3);
    const int mtile = wg >> 4;       // 0..31
    const int ntile = wg & 15;       // 0..15
    const int m0 = mtile * 256, n0 = ntile * 256;

    __shared__ __align__(16) unsigned short ldsA[2 * 2 * 128 * 64];  // 64 KiB
    __shared__ __align__(16) unsigned short ldsB[2 * 2 * 128 * 64];  // 64 KiB

    // --- staging (write side): linear LDS dest, inverse-swizzled global src
    const int lr8 = lane >> 3;             // 0..7
    const int cch = (lane & 7) ^ lr8;      // swizzled 16B-chunk index
    const unsigned short* aSb = A + (size_t)(m0 + lr8) * K_DIM + cch * 8;
    const unsigned short* bSb = B + (size_t)(n0 + lr8) * K_DIM + cch * 8;

    auto stageA = [&](int par_, int h, int kt) {
#pragma unroll
        for (int s = 0; s < 2; ++s) {
            const int j = wid * 2 + s;
            const unsigned short* g = aSb + (size_t)(h * 128 + j * 8) * K_DIM + kt * 64;
            __builtin_amdgcn_global_load_lds(
                (const __attribute__((address_space(1))) void*)g,
                (__attribute__((address_space(3))) void*)(ldsA + (par_ * 2 + h) * 8192 + j * 512),
                16, 0, 0);
        }
    };
    auto stageB = [&](int par_, int h, int kt) {
#pragma unroll
        for (int s = 0; s < 2; ++s) {
            const int j = wid * 2 + s;
            const unsigned short* g = bSb + (size_t)(h * 128 + j * 8) * K_DIM + kt * 64;
            __builtin_amdgcn_global_load_lds(
                (const __attribute__((address_space(1))) void*)g,
                (__attribute__((address_space(3))) void*)(ldsB + (par_ * 2 + h) * 8192 + j * 512),
                16, 0, 0);
        }
    };

    // --- read side (T2 swizzle on the byte address) ---
    const int rowByte = (lane & 15) * 128;
    const int swz = (lane & 7) << 4;
    const int kc0 = (0 * 64 + (lane >> 4) * 16) ^ swz;
    const int kc1 = (1 * 64 + (lane >> 4) * 16) ^ swz;
    const int baseBoff = (wc & 1) * 4096;  // 64-row sub-block within 128-row half (elements)

    auto readA = [&](int par_, int mf, int kk) -> bf16x8 {
        const char* p = (const char*)(ldsA + (par_ * 2 + wr) * 8192 + mf * 1024) +
                        rowByte + (kk ? kc1 : kc0);
        return *(const bf16x8*)p;
    };
    auto readB = [&](int par_, int nf, int kk) -> bf16x8 {
        const char* p = (const char*)(ldsB + (par_ * 2 + (wc >> 1)) * 8192 + baseBoff + nf * 1024) +
                        rowByte + (kk ? kc1 : kc0);
        return *(const bf16x8*)p;
    };

    f32x4 acc[8][4] = {};
    bf16x8 a[4][2], b[4][2];

    auto mfmaQ = [&](int qm, int qn) {
#pragma unroll
        for (int i = 0; i < 4; ++i)
#pragma unroll
            for (int jn = 0; jn < 2; ++jn)
#pragma unroll
                for (int kk = 0; kk < 2; ++kk)
                    acc[qm * 4 + i][qn * 2 + jn] = __builtin_amdgcn_mfma_f32_16x16x32_bf16(
                        a[i][kk], b[qn * 2 + jn][kk], acc[qm * 4 + i][qn * 2 + jn], 0, 0, 0);
    };

    // --- prologue: t0 fully + t1 fully issued; drain to t1's 8 loads ---
    stageB(0, 0, 0); stageB(0, 1, 0); stageA(0, 0, 0); stageA(0, 1, 0);
    stageB(1, 0, 1); stageB(1, 1, 1); stageA(1, 0, 1); stageA(1, 1, 1);
    WAITV8();
    PH_BAR();

#define KTILE(kt, par)                                                          \
    {                                                                           \
        /* p1: read A-frags 0-3 + B-frags 0-1; MFMA q(0,0) */                   \
        _Pragma("unroll") for (int i = 0; i < 4; ++i)                           \
            _Pragma("unroll") for (int kk = 0; kk < 2; ++kk)                    \
                a[i][kk] = readA(par, i, kk);                                    \
        _Pragma("unroll") for (int nf = 0; nf < 2; ++nf)                        \
            _Pragma("unroll") for (int kk = 0; kk < 2; ++kk)                    \
                b[nf][kk] = readB(par, nf, kk);                                  \
        PH_BAR();                                                               \
        __builtin_amdgcn_s_setprio(1); mfmaQ(0, 0); __builtin_amdgcn_s_setprio(0); \
        PH_BAR();                                                               \
        /* p2: read B-frags 2-3; MFMA q(0,1) */                                 \
        _Pragma("unroll") for (int nf = 2; nf < 4; ++nf)                        \
            _Pragma("unroll") for (int kk = 0; kk < 2; ++kk)                    \
                b[nf][kk] = readB(par, nf, kk);                                  \
        PH_BAR();                                                               \
        __builtin_amdgcn_s_setprio(1); mfmaQ(0, 1); __builtin_amdgcn_s_setprio(0); \
        PH_BAR();                                                               \
        /* p3: read A-frags 4-7; issue t+2 B-halves; MFMA q(1,0) */             \
        _Pragma("unroll") for (int i = 0; i < 4; ++i)                           \
            _Pragma("unroll") for (int kk = 0; kk < 2; ++kk)                    \
                a[i][kk] = readA(par, 4 + i, kk);                                \
        if ((kt) + 2 < NT) { stageB(par, 0, (kt) + 2); stageB(par, 1, (kt) + 2); } \
        PH_BAR();                                                               \
        __builtin_amdgcn_s_setprio(1); mfmaQ(1, 0); __builtin_amdgcn_s_setprio(0); \
        PH_BAR();                                                               \
        /* p4: issue t+2 A-halves; counted vmcnt; MFMA q(1,1) */                \
        if ((kt) + 2 < NT) { stageA(par, 0, (kt) + 2); stageA(par, 1, (kt) + 2); WAITV8(); } \
        else { WAITV0(); }                                                      \
        PH_BAR();                                                               \
        __builtin_amdgcn_s_setprio(1); mfmaQ(1, 1); __builtin_amdgcn_s_setprio(0); \
        PH_BAR();                                                               \
    }

#pragma unroll 1
    for (int kt = 0; kt < NT; kt += 2) {
        KTILE(kt, 0);
        KTILE(kt + 1, 1);
    }
#undef KTILE

    // --- epilogue: C = acc + (b + lora_bias), verified C/D layout ---
#pragma unroll
    for (int nf = 0; nf < 4; ++nf) {
        const int gc = n0 + wc * 64 + nf * 16 + (lane & 15);
        const float bv = bvec[gc] + lbvec[gc];
#pragma unroll
        for (int mf = 0; mf < 8; ++mf) {
            const int gr0 = m0 + wr * 128 + mf * 16 + (lane >> 4) * 4;
            f32x4 v = acc[mf][nf];
#pragma unroll
            for (int j = 0; j < 4; ++j)
                C[(size_t)(gr0 + j) * N_DIM + gc] = v[j] + bv;
        }
    }
}

// --- Fallback: naive fp32 (only if ws too small) ----------------------------
__global__ __launch_bounds__(256) void naive_kernel(
    const float* __restrict__ x, const float* __restrict__ W,
    const float* __restrict__ b, const float* __restrict__ lA,
    const float* __restrict__ lB, const float* __restrict__ lb,
    float* __restrict__ out) {
    __shared__ float xs[K_DIM];
    __shared__ float ts[16];
    const int m = blockIdx.x;
    const int tid = threadIdx.x;
    for (int k = tid; k < K_DIM; k += 256) xs[k] = x[(size_t)m * K_DIM + k];
    if (tid < 16) ts[tid] = 0.f;
    __syncthreads();
    float part[16] = {};
    for (int k = tid * 16; k < tid * 16 + 16; ++k) {
        float xv = xs[k];
#pragma unroll
        for (int r = 0; r < 16; ++r) part[r] += xv * lA[(size_t)r * K_DIM + k];
    }
#pragma unroll
    for (int r = 0; r < 16; ++r) atomicAdd(&ts[r], part[r]);
    __syncthreads();
    const int n = blockIdx.y * 256 + tid;
    float acc = b[n] + lb[n];
#pragma unroll
    for (int r = 0; r < 16; ++r) acc += ts[r] * lB[(size_t)n * 16 + r];
    const float* wrow = W + (size_t)n * K_DIM;
    for (int k = 0; k < K_DIM; ++k) acc += xs[k] * wrow[k];
    out[(size_t)m * N_DIM + n] = acc;
}

// ---------------------------------------------------------------------------
extern "C" void kernel_launch(void* const* d_in, const int* in_sizes, int n_in,
                              void* d_out, int out_size, void* d_ws, size_t ws_size,
                              hipStream_t stream) {
    const float* x  = (const float*)d_in[0];
    const float* W  = (const float*)d_in[1];
    const float* b  = (const float*)d_in[2];
    const float* lA = (const float*)d_in[3];
    const float* lB = (const float*)d_in[4];
    const float* lb = (const float*)d_in[5];
    float* out = (float*)d_out;

    const size_t xb_bytes = (size_t)M_DIM * K_DIM * 2;  // 64 MiB
    const size_t wb_bytes = (size_t)N_DIM * K_DIM * 2;  // 32 MiB

    if (ws_size >= xb_bytes + wb_bytes) {
        unsigned short* xb = (unsigned short*)d_ws;
        unsigned short* wb = (unsigned short*)((char*)d_ws + xb_bytes);

        conv_x_kernel<<<(M_DIM * K_DIM) / (256 * 8), 256, 0, stream>>>(x, xb);
        conv_w_kernel<<<N_DIM / 4, 512, 0, stream>>>(W, lA, lB, wb);

        gemm_kernel<<<(M_DIM / 256) * (N_DIM / 256), 512, 0, stream>>>(xb, wb, b, lb, out);
    } else {
        dim3 grid(M_DIM, N_DIM / 256);
        naive_kernel<<<grid, 256, 0, stream>>>(x, W, b, lA, lB, lb, out);
    }
}